// Round 2
// baseline (128.073 us; speedup 1.0000x reference)
//
#include <hip/hip_runtime.h>

// TF-IDF: out[b, v] = tf[b, v] * idf[v] / sum_s idf[x[b,s]]
//   x:   (512, 1024) int32 token ids, idf: (50257,) fp32
//   out: (512, 50257) fp32   -- 98% zeros (<=1024 nonzeros per row)
//
// Round 2 structure: zero + sparse scatter, no LDS histogram.
//   phase 1: each block streams zeros over its own row with ALIGNED float4
//            stores (same pattern as the 6.4 TB/s fill kernel; round-1's
//            LDS-read + idf-gather + scalar-store loop only hit 0.93 TB/s).
//   phase 2: after __syncthreads (which drains vmcnt, ordering the zero
//            stores at L2 before the atomics), scatter-add the <=1024
//            nonzeros: atomicAdd(orow+tok, idf[tok]*inv_n). Every address
//            only ever accumulates copies of the SAME value, so FP ordering
//            is benign. Row b is touched only by block b -> no cross-block
//            coherence dependency.
// LDS ~70 B -> occupancy limited by threads: 2 blocks/CU, grid 512 = one
// round over 256 CUs.

constexpr int VOCAB = 50257;
constexpr int SEQ = 1024;
constexpr int BATCH = 512;
constexpr int NT = 1024;   // one token per thread

__global__ __launch_bounds__(NT)
void tfidf_kernel(const int* __restrict__ x,
                  const float* __restrict__ idf,
                  float* __restrict__ out) {
    __shared__ float red[NT / 64];
    __shared__ float s_inv_n;

    const int b   = blockIdx.x;
    const int tid = threadIdx.x;

    // Issue the token + idf gathers up front; latency hides behind the
    // zero-streaming loop below.
    const int   tok    = x[(size_t)b * SEQ + tid];
    const float my_idf = idf[tok];

    float* __restrict__ orow = out + (size_t)b * VOCAB;

    // --- phase 1: zero the row with aligned float4 stores ---------------
    // row byte offset mod 16: (b*50257) % 4 == b % 4 floats.
    const int head = (4 - (b & 3)) & 3;            // scalar floats to align
    const int n4   = (VOCAB - head) >> 2;          // aligned float4 count
    const int tail = VOCAB - head - (n4 << 2);

    if (tid < head) orow[tid] = 0.0f;
    float4* __restrict__ p4 = (float4*)(orow + head);
    const float4 z4 = make_float4(0.0f, 0.0f, 0.0f, 0.0f);
    for (int c = tid; c < n4; c += NT) p4[c] = z4;   // <=13 iters, pure stores
    if (tid < tail) orow[head + (n4 << 2) + tid] = 0.0f;

    // --- normalizer: n = sum_s idf[x[b,s]] ------------------------------
    float v = my_idf;
    #pragma unroll
    for (int off = 32; off > 0; off >>= 1) v += __shfl_down(v, off, 64);
    if ((tid & 63) == 0) red[tid >> 6] = v;
    __syncthreads();                 // also orders zero-stores before atomics
    if (tid == 0) {
        float n = 0.0f;
        #pragma unroll
        for (int w = 0; w < NT / 64; ++w) n += red[w];
        s_inv_n = 1.0f / n;
    }
    __syncthreads();

    // --- phase 2: sparse scatter of the nonzeros ------------------------
    atomicAdd(orow + tok, my_idf * s_inv_n);
}

extern "C" void kernel_launch(void* const* d_in, const int* in_sizes, int n_in,
                              void* d_out, int out_size, void* d_ws, size_t ws_size,
                              hipStream_t stream) {
    const int*   x   = (const int*)d_in[0];
    const float* idf = (const float*)d_in[1];
    float*       out = (float*)d_out;
    tfidf_kernel<<<dim3(BATCH), dim3(NT), 0, stream>>>(x, idf, out);
}

// Round 3
// 114.172 us; speedup vs baseline: 1.1218x; 1.1218x over previous
//
#include <hip/hip_runtime.h>

// TF-IDF: out[b, v] = tf[b, v] * idf[v] / sum_s idf[x[b,s]]
//   x: (512,1024) int32, idf: (50257,) fp32, out: (512,50257) fp32
//
// Round 3: LDS-staged segments. Grid = 512 rows x 4 segments, 256 threads.
//  - Each block stages its ~12565-float segment in LDS (50.3 KB -> 3
//    blocks/CU resident, 8 queued/CU: store-drain overlaps next block's
//    compute, unlike rounds 1-2's single round of 1024-thread blocks).
//  - Zero LDS, scan the row's 1024 tokens (4/thread, int4), LDS-atomicAdd
//    idf[tok]*inv_n for in-segment tokens (~256 hits/block; each LDS slot
//    accumulates copies of the same value -> deterministic).
//  - inv_n recomputed identically in all 4 blocks of a row (same gather
//    order -> bitwise-same), avoiding a separate kernel + sync.
//  - Stream segment to global with ALIGNED float4 stores; every output
//    byte written exactly once; no global atomics, no RMW traffic.

constexpr int VOCAB  = 50257;
constexpr int SEQ    = 1024;
constexpr int BATCH  = 512;
constexpr int NSEG   = 4;
constexpr int SEGLEN = (VOCAB + NSEG - 1) / NSEG;   // 12565
constexpr int NT     = 256;

__global__ __launch_bounds__(NT)
void tfidf_kernel(const int* __restrict__ x,
                  const float* __restrict__ idf,
                  float* __restrict__ out) {
    __shared__ float seg[SEGLEN];        // 50,260 B
    __shared__ float red[NT / 64];

    const int blk = blockIdx.x;
    const int b   = blk >> 2;            // row
    const int s   = blk & 3;             // segment index
    const int tid = threadIdx.x;

    const int lo  = s * SEGLEN;
    const int len = (SEGLEN < VOCAB - lo) ? SEGLEN : (VOCAB - lo);

    // ---- this thread's 4 tokens (coalesced int4; row is 4KB-aligned) ----
    const int4 t4 = ((const int4*)(x + (size_t)b * SEQ))[tid];

    // ---- zero the LDS segment (16B-aligned vector writes) ---------------
    {
        float4* z = (float4*)seg;
        const float4 z4 = make_float4(0.f, 0.f, 0.f, 0.f);
        for (int c = tid; c < SEGLEN / 4; c += NT) z[c] = z4;   // 3141 f4
        if (tid < SEGLEN - (SEGLEN / 4) * 4) seg[(SEGLEN / 4) * 4 + tid] = 0.f;
    }

    // ---- normalizer: gather idf for all 4 tokens (reused by scatter) ----
    const float i0 = idf[t4.x], i1 = idf[t4.y], i2 = idf[t4.z], i3 = idf[t4.w];
    float v = (i0 + i1) + (i2 + i3);
    #pragma unroll
    for (int off = 32; off > 0; off >>= 1) v += __shfl_down(v, off, 64);
    if ((tid & 63) == 0) red[tid >> 6] = v;
    __syncthreads();                      // orders LDS zeroing + partials
    const float inv_n = 1.0f / ((red[0] + red[1]) + (red[2] + red[3]));

    // ---- scatter in-segment tokens into LDS ------------------------------
    if (t4.x >= lo && t4.x < lo + len) atomicAdd(&seg[t4.x - lo], i0 * inv_n);
    if (t4.y >= lo && t4.y < lo + len) atomicAdd(&seg[t4.y - lo], i1 * inv_n);
    if (t4.z >= lo && t4.z < lo + len) atomicAdd(&seg[t4.z - lo], i2 * inv_n);
    if (t4.w >= lo && t4.w < lo + len) atomicAdd(&seg[t4.w - lo], i3 * inv_n);
    __syncthreads();

    // ---- stream segment to global: head / aligned float4 / tail ---------
    const size_t g0 = (size_t)b * VOCAB + lo;     // g0 % 4 == (b + s) % 4
    float* __restrict__ o = out + g0;
    const int head = (int)((4 - (g0 & 3)) & 3);
    const int n4   = (len - head) >> 2;
    const int tail = len - head - (n4 << 2);

    if (tid < head) o[tid] = seg[tid];
    float4* __restrict__ p4 = (float4*)(o + head);
    for (int c = tid; c < n4; c += NT) {          // ~12 iters/thread
        const int i = head + (c << 2);
        p4[c] = make_float4(seg[i], seg[i + 1], seg[i + 2], seg[i + 3]);
    }
    if (tid < tail) {
        const int i = head + (n4 << 2) + tid;
        o[i] = seg[i];
    }
}

extern "C" void kernel_launch(void* const* d_in, const int* in_sizes, int n_in,
                              void* d_out, int out_size, void* d_ws, size_t ws_size,
                              hipStream_t stream) {
    const int*   x   = (const int*)d_in[0];
    const float* idf = (const float*)d_in[1];
    float*       out = (float*)d_out;
    tfidf_kernel<<<dim3(BATCH * NSEG), dim3(NT), 0, stream>>>(x, idf, out);
}